// Round 1
// baseline (3203.072 us; speedup 1.0000x reference)
//
#include <hip/hip_runtime.h>

#define BATCH   2048
#define SEQLEN  2048
#define EMB     50
#define HID     50
#define GATES   200   // 4*HID
#define KHALF   28    // padded half of K: 28+28 = 56 >= 50

__device__ __forceinline__ float fast_sigmoid(float x) {
    return 1.0f / (1.0f + __expf(-x));
}

__device__ __forceinline__ float fast_tanh(float x) {
    // tanh(x) = (e^{2x}-1)/(e^{2x}+1), clamp to avoid inf/inf
    float x2 = fminf(fmaxf(2.0f * x, -30.0f), 30.0f);
    float e = __expf(x2);
    return (e - 1.0f) / (e + 1.0f);
}

// Ttab[v][g] = sum_e embed[v][e]*W_ih[g][e] + b_ih[g] + b_hh[g]
__global__ void build_table(const float* __restrict__ embed,
                            const float* __restrict__ Wih,
                            const float* __restrict__ bih,
                            const float* __restrict__ bhh,
                            float* __restrict__ Ttab) {
    int idx = blockIdx.x * blockDim.x + threadIdx.x;
    if (idx >= 13 * GATES) return;
    int v = idx / GATES;
    int g = idx - v * GATES;
    float a = bih[g] + bhh[g];
    #pragma unroll 10
    for (int e = 0; e < EMB; ++e)
        a = fmaf(embed[v * EMB + e], Wih[g * EMB + e], a);
    Ttab[idx] = a;
}

// One block (512 threads) per batch element.
// thread -> (row = tid>>1 in [0,256), khalf = tid&1); rows >= 200 inactive.
// Each thread keeps its 28-float W_hh row-slice in registers for all 2048 steps.
__global__ __launch_bounds__(512) void lstm_main(
    const int*   __restrict__ x,
    const float* __restrict__ Whh,
    const float* __restrict__ Ttab,
    const float* __restrict__ W1,
    const float* __restrict__ b1,
    const float* __restrict__ W2,
    const float* __restrict__ b2,
    float*       __restrict__ out)
{
    const int b   = blockIdx.x;
    const int tid = threadIdx.x;
    const int row = tid >> 1;
    const int kh  = tid & 1;
    const bool rowActive = row < GATES;

    __shared__ __align__(16) float h_s[2 * KHALF];  // padded hidden state
    __shared__ float g_s[GATES];                    // pre-activation gates

    // Load register-resident W_hh slice (zero-padded beyond k=50)
    float w[KHALF];
    #pragma unroll
    for (int i = 0; i < KHALF; ++i) {
        int k = kh * KHALF + i;
        w[i] = (rowActive && k < HID) ? Whh[row * HID + k] : 0.0f;
    }

    if (tid < 2 * KHALF) h_s[tid] = 0.0f;   // h = 0 (incl. pad, stays 0)
    float c = 0.0f;                          // thread u<50 owns cell state c[u]
    __syncthreads();

    const int* xrow = x + (long)b * SEQLEN;
    const float4* hv = (const float4*)(h_s + kh * KHALF);

    for (int t = 0; t < SEQLEN; ++t) {
        const int tok = xrow[t];             // block-uniform -> scalar load
        float tb = 0.0f;
        if (rowActive && kh == 0)
            tb = Ttab[tok * GATES + row];    // L1-resident 10.4KB table

        // Partial dot: 28 FMAs against h broadcast from LDS
        float acc = 0.0f;
        #pragma unroll
        for (int i = 0; i < KHALF / 4; ++i) {
            float4 h4 = hv[i];
            acc = fmaf(w[4 * i + 0], h4.x, acc);
            acc = fmaf(w[4 * i + 1], h4.y, acc);
            acc = fmaf(w[4 * i + 2], h4.z, acc);
            acc = fmaf(w[4 * i + 3], h4.w, acc);
        }
        acc += __shfl_xor(acc, 1, 64);       // combine k-halves (adjacent lanes)
        if (rowActive && kh == 0)
            g_s[row] = acc + tb;
        __syncthreads();

        // Gate activations + state update: one thread per hidden unit
        if (tid < HID) {
            float gi = g_s[tid];
            float gf = g_s[HID + tid];
            float gg = g_s[2 * HID + tid];
            float go = g_s[3 * HID + tid];
            float iv = fast_sigmoid(gi);
            float fv = fast_sigmoid(gf);
            float gv = fast_tanh(gg);
            float ov = fast_sigmoid(go);
            c = fv * c + iv * gv;
            h_s[tid] = ov * fast_tanh(c);
        }
        __syncthreads();
    }

    // Epilogue MLP: h -> relu(W1 h + b1) -> W2 . + b2 (runs once, cost trivial)
    if (tid < HID) {
        float a = b1[tid];
        #pragma unroll 10
        for (int k = 0; k < HID; ++k)
            a = fmaf(W1[tid * HID + k], h_s[k], a);
        g_s[tid] = fmaxf(a, 0.0f);
    }
    __syncthreads();
    if (tid == 0) {
        float a = b2[0];
        #pragma unroll 10
        for (int k = 0; k < HID; ++k)
            a = fmaf(W2[k], g_s[k], a);
        out[b] = a;
    }
}

extern "C" void kernel_launch(void* const* d_in, const int* in_sizes, int n_in,
                              void* d_out, int out_size, void* d_ws, size_t ws_size,
                              hipStream_t stream) {
    const int*   x     = (const int*)  d_in[0];
    const float* embed = (const float*)d_in[1];
    const float* W_ih  = (const float*)d_in[2];
    const float* W_hh  = (const float*)d_in[3];
    const float* b_ih  = (const float*)d_in[4];
    const float* b_hh  = (const float*)d_in[5];
    const float* W1    = (const float*)d_in[6];
    const float* b1    = (const float*)d_in[7];
    const float* W2    = (const float*)d_in[8];
    const float* b2    = (const float*)d_in[9];
    float* out = (float*)d_out;

    float* Ttab = (float*)d_ws;  // 13*200*4 = 10.4 KB

    build_table<<<(13 * GATES + 255) / 256, 256, 0, stream>>>(
        embed, W_ih, b_ih, b_hh, Ttab);

    lstm_main<<<BATCH, 512, 0, stream>>>(
        x, W_hh, Ttab, W1, b1, W2, b2, out);
}

// Round 2
// 1611.716 us; speedup vs baseline: 1.9874x; 1.9874x over previous
//
#include <hip/hip_runtime.h>

#define T_SEQ   2048
#define HID     50
#define NGATES  200
#define NPAD    208     // 13 tiles of 16
#define KPAD    128
#define MB      8       // batch rows per block
#define NBLK    256     // 2048 / MB
#define MPAD    12      // G m-stride (floats): 2-way-bank-free, 16B-aligned float4 stores
#define HSTR    136     // hA row stride in ushorts (=272B, 16B-aligned, bank-balanced)

typedef __attribute__((ext_vector_type(8))) short  short8;
typedef __attribute__((ext_vector_type(4))) float  f32x4;

__device__ __forceinline__ ushort bf_hi(float f) {
    unsigned u = __float_as_uint(f);
    u += 0x7FFFu + ((u >> 16) & 1u);          // RNE to bf16
    return (ushort)(u >> 16);
}
__device__ __forceinline__ float bf2f(ushort h) {
    return __uint_as_float(((unsigned)h) << 16);
}
__device__ __forceinline__ ushort bf_lo(float f) {
    return bf_hi(f - bf2f(bf_hi(f)));
}
__device__ __forceinline__ float sigm(float x) {
    return 1.f / (1.f + __expf(-x));
}
__device__ __forceinline__ float tanh_(float x) {
    float xc = fminf(fmaxf(x, -15.f), 15.f);
    float e = __expf(2.f * xc);
    return (e - 1.f) / (e + 1.f);
}

// B matrix [NPAD][KPAD] bf16 (ushort bits), K-augmented:
//  k in [0,50)    : W_hh_hi[n][k]         (x h_hi)
//  k in [50,100)  : W_hh_hi[n][k-50]      (x h_lo)
//  k in [100,113) : Ttab_hi[v=k-100][n]   (x onehot)   Ttab[v][n]=sum_e embed[v,e]*W_ih[n,e]
//  k in [113,126) : Ttab_lo[v=k-113][n]   (x onehot)
//  k == 126       : (b_ih+b_hh)_hi        (x 1)
//  k == 127       : (b_ih+b_hh)_lo        (x 1)
__global__ void build_B(const float* __restrict__ embed,
                        const float* __restrict__ Wih,
                        const float* __restrict__ Whh,
                        const float* __restrict__ bih,
                        const float* __restrict__ bhh,
                        ushort* __restrict__ B) {
    int idx = blockIdx.x * blockDim.x + threadIdx.x;
    if (idx >= NPAD * KPAD) return;
    int n = idx >> 7;
    int k = idx & 127;
    ushort v = 0;
    if (n < NGATES) {
        if (k < 100) {
            int kk = (k < 50) ? k : (k - 50);
            v = bf_hi(Whh[n * HID + kk]);
        } else if (k < 126) {
            int vv = (k < 113) ? (k - 100) : (k - 113);
            float t = 0.f;
            for (int e = 0; e < HID; ++e)
                t = fmaf(embed[vv * HID + e], Wih[n * HID + e], t);
            v = (k < 113) ? bf_hi(t) : bf_lo(t);
        } else {
            float bb = bih[n] + bhh[n];
            v = (k == 126) ? bf_hi(bb) : bf_lo(bb);
        }
    }
    B[idx] = v;
}

// 256 blocks x 512 threads; block handles batch rows [blockIdx.x*8, +8).
__global__ __launch_bounds__(512) void lstm_mfma(
    const int*    __restrict__ x,
    const ushort* __restrict__ Bmat,
    const float*  __restrict__ W1,
    const float*  __restrict__ b1,
    const float*  __restrict__ W2,
    const float*  __restrict__ b2,
    float*        __restrict__ out)
{
    const int t   = threadIdx.x;
    const int w   = t >> 6;
    const int l   = t & 63;
    const int c16 = l & 15;     // MFMA: A row m / B,C col n
    const int q   = l >> 4;     // MFMA: k-group / C row-group
    const int m   = t & 7;      // act: batch row
    const int u   = t >> 3;     // act: hidden unit (valid if t<400)
    const bool actv = (t < 400);

    __shared__ __align__(16) ushort hA[MB * HSTR];
    __shared__ __align__(16) float  G[NPAD * MPAD];

    // tile partition over 8 waves: {2,2,2,2,2,1,1,1}
    const int ntile  = (w < 5) ? 2 : 1;
    const int tstart = (w < 5) ? (2 * w) : (10 + (w - 5));

    short8 bf[2][4];
    for (int j = 0; j < 2; ++j) {
        if (j < ntile) {
            int n = (tstart + j) * 16 + c16;
            for (int kf = 0; kf < 4; ++kf)
                bf[j][kf] = *(const short8*)(Bmat + n * KPAD + kf * 32 + q * 8);
        }
    }

    for (int i = t; i < MB * HSTR; i += 512) hA[i] = 0;

    const long xbase = (long)blockIdx.x * MB * T_SEQ;
    int tok_cur = 0, tok_nxt = 0;
    if (t < MB) {
        tok_cur = x[xbase + (long)m * T_SEQ + 0];
        tok_nxt = x[xbase + (long)m * T_SEQ + 1];
    }
    __syncthreads();
    if (t < MB) {
        hA[m * HSTR + 126] = 0x3F80;
        hA[m * HSTR + 127] = 0x3F80;
        hA[m * HSTR + 100 + tok_cur] = 0x3F80;
        hA[m * HSTR + 113 + tok_cur] = 0x3F80;
    }
    float c = 0.f;

    const ushort* hrow = hA + c16 * HSTR;   // only c16<8 dereferenced
    const short8 zero8 = {0, 0, 0, 0, 0, 0, 0, 0};

    for (int step = 0; step < T_SEQ; ++step) {
        __syncthreads();  // hA ready

        short8 a[4];
        if (c16 < 8) {
            #pragma unroll
            for (int kf = 0; kf < 4; ++kf)
                a[kf] = *(const short8*)(hrow + kf * 32 + q * 8);
        } else {
            #pragma unroll
            for (int kf = 0; kf < 4; ++kf) a[kf] = zero8;
        }

        #pragma unroll
        for (int j = 0; j < 2; ++j) {
            if (j < ntile) {
                f32x4 z = {0.f, 0.f, 0.f, 0.f};
                z = __builtin_amdgcn_mfma_f32_16x16x32_bf16(a[0], bf[j][0], z, 0, 0, 0);
                z = __builtin_amdgcn_mfma_f32_16x16x32_bf16(a[1], bf[j][1], z, 0, 0, 0);
                z = __builtin_amdgcn_mfma_f32_16x16x32_bf16(a[2], bf[j][2], z, 0, 0, 0);
                z = __builtin_amdgcn_mfma_f32_16x16x32_bf16(a[3], bf[j][3], z, 0, 0, 0);
                if (q < 2) {
                    int n = (tstart + j) * 16 + c16;
                    *(f32x4*)(G + n * MPAD + q * 4) = z;
                }
            }
        }
        __syncthreads();  // G ready

        if (actv) {
            float gi = G[u * MPAD + m];
            float gf = G[(50 + u) * MPAD + m];
            float gg = G[(100 + u) * MPAD + m];
            float go = G[(150 + u) * MPAD + m];
            float iv = sigm(gi);
            float fv = sigm(gf);
            float gv = tanh_(gg);
            float ov = sigm(go);
            c = fv * c + iv * gv;
            float h = ov * tanh_(c);
            ushort hh = bf_hi(h);
            hA[m * HSTR + u]      = hh;
            hA[m * HSTR + 50 + u] = bf_hi(h - bf2f(hh));
        }
        if (t < MB) {
            int pf = 0;
            if (step + 2 < T_SEQ) pf = x[xbase + (long)m * T_SEQ + step + 2];
            hA[m * HSTR + 100 + tok_cur] = 0;
            hA[m * HSTR + 113 + tok_cur] = 0;
            if (step + 1 < T_SEQ) {
                hA[m * HSTR + 100 + tok_nxt] = 0x3F80;
                hA[m * HSTR + 113 + tok_nxt] = 0x3F80;
            }
            tok_cur = tok_nxt;
            tok_nxt = pf;
        }
    }

    __syncthreads();
    if (actv) {
        float a = b1[u];
        const float* wr = W1 + u * HID;
        #pragma unroll 10
        for (int k = 0; k < HID; ++k) {
            float hk = bf2f(hA[m * HSTR + k]) + bf2f(hA[m * HSTR + 50 + k]);
            a = fmaf(wr[k], hk, a);
        }
        G[u * MPAD + m] = fmaxf(a, 0.f);
    }
    __syncthreads();
    if (t < MB) {
        float a = b2[0];
        #pragma unroll 10
        for (int j = 0; j < HID; ++j)
            a = fmaf(W2[j], G[j * MPAD + m], a);
        out[blockIdx.x * MB + m] = a;
    }
}

extern "C" void kernel_launch(void* const* d_in, const int* in_sizes, int n_in,
                              void* d_out, int out_size, void* d_ws, size_t ws_size,
                              hipStream_t stream) {
    const int*   x     = (const int*)  d_in[0];
    const float* embed = (const float*)d_in[1];
    const float* W_ih  = (const float*)d_in[2];
    const float* W_hh  = (const float*)d_in[3];
    const float* b_ih  = (const float*)d_in[4];
    const float* b_hh  = (const float*)d_in[5];
    const float* W1    = (const float*)d_in[6];
    const float* b1    = (const float*)d_in[7];
    const float* W2    = (const float*)d_in[8];
    const float* b2    = (const float*)d_in[9];
    float* out = (float*)d_out;

    ushort* Bmat = (ushort*)d_ws;  // NPAD*KPAD*2 = 53,248 B scratch

    build_B<<<(NPAD * KPAD + 255) / 256, 256, 0, stream>>>(
        embed, W_ih, W_hh, b_ih, b_hh, Bmat);

    lstm_mfma<<<NBLK, 512, 0, stream>>>(
        x, Bmat, W1, b1, W2, b2, out);
}